// Round 2
// baseline (24824.557 us; speedup 1.0000x reference)
//
#include <hip/hip_runtime.h>

#define UNITS 65
#define SEQ   8192
#define BATCH 50
#define CHS   20          // chunk stride in floats (17 payload + 3 pad, keeps b128 aligned)
#define VBUF  160         // 8 chunks * 20 floats

__device__ __forceinline__ float frcp(float x){ return __builtin_amdgcn_rcpf(x); }
__device__ __forceinline__ float fsigmoid(float x){ return frcp(1.0f + __expf(-x)); }
__device__ __forceinline__ float ftanh(float x){
    float e2 = __expf(2.0f * x);
    return 1.0f - 2.0f * frcp(e2 + 1.0f);
}

// DPP add: x += lane-permuted x, on the VALU pipe (no LDS traffic)
template<int CTRL>
__device__ __forceinline__ float dppadd(float x){
    int t = __builtin_amdgcn_update_dpp(0, __float_as_int(x), CTRL, 0xF, 0xF, true);
    return x + __int_as_float(t);
}
// Sum over each aligned group of 8 lanes; valid result in lanes with (lane&7)==7.
// quad_perm xor1, xor2 make every lane its quad-sum; row_shr:4 (dst[i]=src[i-4])
// flows the low quad's sum up to the high quad.
__device__ __forceinline__ float red8(float x){
    x = dppadd<0xB1>(x);    // quad_perm [1,0,3,2]
    x = dppadd<0x4E>(x);    // quad_perm [2,3,0,1]
    x = dppadd<0x114>(x);   // row_shr:4
    return x;
}

// weight of concatenated [W;U] at padded-k row (K=136: 0..67 -> W rows 0..64, 68..135 -> U rows)
__device__ __forceinline__ float wt(const float* W, const float* U, int k, int c){
    if (k < 68) return (k < 65) ? W[k * 260 + c] : 0.0f;
    int r = k - 68;
    return (r < 65) ? U[r * 260 + c] : 0.0f;
}

// chunked position of padded v-element k: chunk q=k/17 at q*20 + k%17
__device__ __forceinline__ int inpos(int k){ return (k / 17) * CHS + (k % 17); }

// One block per batch element. 512 threads = 8 waves.
// lane = jl*8 + kq:  unit j = wave*8 + jl (0..63), K-chunk kq (0..7, 17 k each).
// Each thread: 4 gate-partials of unit j over its K-chunk; DPP-reduce over kq;
// lane (kq==7) holds full z_i,f,g,o for unit j and does the state update in-lane.
// Unit 64: waves 0..3 each accumulate one of its 4 gate columns (full K via their
// 8 kq lanes), published through ebuf, updated by wave0/lane7.
__global__ __launch_bounds__(512)
void lstm3_kernel(const float* __restrict__ x, const float* __restrict__ W,
                  const float* __restrict__ U, const float* __restrict__ b,
                  float* __restrict__ out)
{
    const int e    = blockIdx.x;
    const int tid  = threadIdx.x;
    const int wave = tid >> 6, lane = tid & 63;
    const int jl   = lane >> 3, kq = lane & 7;
    const int j    = wave * 8 + jl;
    const bool upd = (kq == 7);
    const bool u64 = (wave == 0 && lane == 7);

    __shared__ __attribute__((aligned(16))) float vbuf[2 * VBUF];  // ping-pong chunked v
    __shared__ __attribute__((aligned(16))) float ebuf[4];         // unit-64 gate z's

    // ---- per-thread weights in registers ----
    float2 wA[17], wB[17];   // gates (i,f) and (g,o) of unit j
    float  xw[17];           // extra column for unit 64 (waves 0..3)
    const int xc = (wave & 3) * 65 + 64;
    #pragma unroll
    for (int kk = 0; kk < 17; ++kk) {
        int k = kq * 17 + kk;
        wA[kk] = make_float2(wt(W, U, k, j),        wt(W, U, k, 65 + j));
        wB[kk] = make_float2(wt(W, U, k, 130 + j),  wt(W, U, k, 195 + j));
        xw[kk] = (wave < 4) ? wt(W, U, k, xc) : 0.0f;
    }

    float bi = 0, bf = 0, bg = 0, bo = 0;
    if (upd) { bi = b[j]; bf = b[65 + j]; bg = b[130 + j]; bo = b[195 + j]; }
    float b64i = 0, b64f = 0, b64g = 0, b64o = 0;
    if (u64) { b64i = b[64]; b64f = b[129]; b64g = b[194]; b64o = b[259]; }

    float h1 = 0, h2 = 0, h3 = 0, c1 = 0, c2 = 0, c3 = 0;          // unit j
    float h1e = 0, h2e = 0, h3e = 0, c1e = 0, c2e = 0, c3e = 0;    // unit 64

    const float* xrow = x   + (size_t)e * SEQ * UNITS;
    float*       orow = out + (size_t)e * SEQ * UNITS;

    const int ipI = inpos(j);        // in-part slot of unit j
    const int ipH = inpos(68 + j);   // h-part slot of unit j
    // unit 64: inpos(64)=73, inpos(132)=153

    // ---- init: zero both buffers (pads must be 0), write x[0] ----
    if (tid < 2 * VBUF) vbuf[tid] = 0.0f;
    __syncthreads();
    if (upd) vbuf[ipI] = xrow[j];
    if (u64) vbuf[73]  = xrow[64];
    __syncthreads();

    int cur = 0;
    float xn = 0.0f, xn64 = 0.0f;
    for (int t = 0; t < SEQ; ++t) {
        #pragma unroll
        for (int cell = 0; cell < 3; ++cell) {
            // ---------- phase A: gate partials ----------
            const float* vp = &vbuf[cur * VBUF + CHS * kq];
            float4 v0 = *(const float4*)(vp);
            float4 v1 = *(const float4*)(vp + 4);
            float4 v2 = *(const float4*)(vp + 8);
            float4 v3 = *(const float4*)(vp + 12);
            float  ve = vp[16];
            float vv[17] = {v0.x, v0.y, v0.z, v0.w, v1.x, v1.y, v1.z, v1.w,
                            v2.x, v2.y, v2.z, v2.w, v3.x, v3.y, v3.z, v3.w, ve};

            float aI = 0, aF = 0, aG = 0, aO = 0;
            #pragma unroll
            for (int kk = 0; kk < 17; ++kk) {
                float s = vv[kk];
                aI = fmaf(s, wA[kk].x, aI);
                aF = fmaf(s, wA[kk].y, aF);
                aG = fmaf(s, wB[kk].x, aG);
                aO = fmaf(s, wB[kk].y, aO);
            }
            if (wave < 4) {
                float ax = 0;
                #pragma unroll
                for (int kk = 0; kk < 17; ++kk) ax = fmaf(vv[kk], xw[kk], ax);
                ax = red8(ax);
                if (lane == 7) ebuf[wave] = ax;
            }
            aI = red8(aI); aF = red8(aF); aG = red8(aG); aO = red8(aO);
            __syncthreads();   // publishes ebuf (and orders next-buf writes after all reads)

            // ---------- phase B: state update ----------
            float* nbuf = &vbuf[(cur ^ 1) * VBUF];
            if (upd) {
                if (cell == 0) xn = (t + 1 < SEQ) ? xrow[(size_t)(t + 1) * UNITS + j] : 0.0f;
                float gi = fsigmoid(aI + bi);
                float gf = fsigmoid(aF + bf);
                float gg = ftanh  (aG + bg);
                float go = fsigmoid(aO + bo);
                if (cell == 0) {
                    c1 = gf * c1 + gi * gg; h1 = go * ftanh(c1);
                    nbuf[ipI] = h1; nbuf[ipH] = h2;       // next v = [h1_new | h2_old]
                } else if (cell == 1) {
                    c2 = gf * c2 + gi * gg; h2 = go * ftanh(c2);
                    nbuf[ipI] = h2; nbuf[ipH] = h3;       // next v = [h2_new | h3_old]
                } else {
                    c3 = gf * c3 + gi * gg; h3 = go * ftanh(c3);
                    orow[(size_t)t * UNITS + j] = h3;
                    nbuf[ipI] = xn; nbuf[ipH] = h1;       // next v = [x_{t+1} | h1]
                }
            }
            if (u64) {
                if (cell == 0) xn64 = (t + 1 < SEQ) ? xrow[(size_t)(t + 1) * UNITS + 64] : 0.0f;
                float4 ez = *(const float4*)ebuf;
                float gi = fsigmoid(ez.x + b64i);
                float gf = fsigmoid(ez.y + b64f);
                float gg = ftanh  (ez.z + b64g);
                float go = fsigmoid(ez.w + b64o);
                if (cell == 0) {
                    c1e = gf * c1e + gi * gg; h1e = go * ftanh(c1e);
                    nbuf[73] = h1e; nbuf[153] = h2e;
                } else if (cell == 1) {
                    c2e = gf * c2e + gi * gg; h2e = go * ftanh(c2e);
                    nbuf[73] = h2e; nbuf[153] = h3e;
                } else {
                    c3e = gf * c3e + gi * gg; h3e = go * ftanh(c3e);
                    orow[(size_t)t * UNITS + 64] = h3e;
                    nbuf[73] = xn64; nbuf[153] = h1e;
                }
            }
            cur ^= 1;
            __syncthreads();
        }
    }
}

// Dense head, in place on d_out: out_row = row @ Wd + bd. One thread per row.
__global__ __launch_bounds__(256)
void dense_kernel(float* __restrict__ io,
                  const float* __restrict__ Wd,
                  const float* __restrict__ bd)
{
    __shared__ __attribute__((aligned(16))) float wS[65 * 68];
    __shared__ float bS[65];
    for (int i = threadIdx.x; i < 65 * 65; i += 256) {
        int r = i / 65, c = i - r * 65;
        wS[r * 68 + c] = Wd[i];
    }
    if (threadIdx.x < 65) bS[threadIdx.x] = bd[threadIdx.x];
    __syncthreads();

    const size_t row  = (size_t)blockIdx.x * 256 + threadIdx.x;
    const size_t base = row * 65;

    float r[65];
    #pragma unroll
    for (int k = 0; k < 65; ++k) r[k] = io[base + k];

    for (int ct = 0; ct < 16; ++ct) {
        const int c = ct * 4;
        float a0 = bS[c], a1 = bS[c + 1], a2 = bS[c + 2], a3 = bS[c + 3];
        #pragma unroll
        for (int k = 0; k < 65; ++k) {
            const float4 wv = *reinterpret_cast<const float4*>(&wS[k * 68 + c]);
            a0 += r[k] * wv.x;
            a1 += r[k] * wv.y;
            a2 += r[k] * wv.z;
            a3 += r[k] * wv.w;
        }
        io[base + c]     = a0;
        io[base + c + 1] = a1;
        io[base + c + 2] = a2;
        io[base + c + 3] = a3;
    }
    float a = bS[64];
    #pragma unroll
    for (int k = 0; k < 65; ++k) a += r[k] * wS[k * 68 + 64];
    io[base + 64] = a;
}

extern "C" void kernel_launch(void* const* d_in, const int* in_sizes, int n_in,
                              void* d_out, int out_size, void* d_ws, size_t ws_size,
                              hipStream_t stream)
{
    const float* x  = (const float*)d_in[0];
    const float* W  = (const float*)d_in[1];
    const float* U  = (const float*)d_in[2];
    const float* b  = (const float*)d_in[3];
    const float* Wd = (const float*)d_in[4];
    const float* bd = (const float*)d_in[5];
    float* out = (float*)d_out;

    hipLaunchKernelGGL(lstm3_kernel, dim3(BATCH), dim3(512), 0, stream, x, W, U, b, out);
    hipLaunchKernelGGL(dense_kernel, dim3(1600), dim3(256), 0, stream, out, Wd, bd);
}

// Round 3
// 19350.394 us; speedup vs baseline: 1.2829x; 1.2829x over previous
//
#include <hip/hip_runtime.h>

#define UNITS 65
#define SEQ   8192
#define BATCH 50

__device__ __forceinline__ float frcp(float x){ return __builtin_amdgcn_rcpf(x); }
__device__ __forceinline__ float fsigmoid(float x){ return frcp(1.0f + __expf(-x)); }
__device__ __forceinline__ float ftanh(float x){
    float e2 = __expf(2.0f * x);
    return 1.0f - 2.0f * frcp(e2 + 1.0f);
}

// DPP helpers (VALU pipe, no LDS traffic)
template<int CTRL>
__device__ __forceinline__ float dppadd(float x){
    int t = __builtin_amdgcn_update_dpp(0, __float_as_int(x), CTRL, 0xF, 0xF, true);
    return x + __int_as_float(t);
}
template<int CTRL>
__device__ __forceinline__ float dppmov(float x){
    int t = __builtin_amdgcn_update_dpp(0, __float_as_int(x), CTRL, 0xF, 0xF, true);
    return __int_as_float(t);
}
// sum over each quad; every lane of the quad gets the full sum
__device__ __forceinline__ float red4_all(float x){
    x = dppadd<0xB1>(x);   // quad_perm [1,0,3,2]
    x = dppadd<0x4E>(x);   // quad_perm [2,3,0,1]
    return x;
}
// canonical 64-lane sum; total lands in lane 63
__device__ __forceinline__ float red64_lane63(float x){
    x = dppadd<0x111>(x);  // row_shr:1
    x = dppadd<0x112>(x);  // row_shr:2
    x = dppadd<0x114>(x);  // row_shr:4
    x = dppadd<0x118>(x);  // row_shr:8
    x = dppadd<0x142>(x);  // row_bcast:15
    x = dppadd<0x143>(x);  // row_bcast:31
    return x;
}
// barrier WITHOUT vmcnt drain (LDS ordering only) — globals here are block-private
__device__ __forceinline__ void bar_lds(){
    asm volatile("s_waitcnt lgkmcnt(0)\n\ts_barrier" ::: "memory");
}

// v layout: k in [0,130): k<65 -> in[k], k>=65 -> h[k-65]; 4 chunks at stride 36
// (chunks of 32,32,32,34; pads zeroed once and never written)
__device__ __forceinline__ int inpos(int k){
    int q = k >> 5; if (q > 3) q = 3;
    return q * 36 + (k - (q << 5));
}
// row k of concatenated [W;U] (K=130), column c
__device__ __forceinline__ float wrow(const float* W, const float* U, int k, int c){
    return (k < 65) ? W[k * 260 + c] : U[(k - 65) * 260 + c];
}

// One block per batch element. 256 threads = 4 waves (1 wave/SIMD).
// lane = jl*4 + kq: unit j = wave*16 + jl (0..63), K-chunk kq (0..3).
// Phase A: per-thread 4 gate-partials over 34-float chunk; red4 -> whole quad has z_i,f,g,o.
//   Unit 64: wave w computes gate-w column split over 64 lanes, red64 -> ebuf[w].
// Phase B: ONE uniform activation block (gate = a*sigmoid(s*z)+d) covers all lanes;
//   kq==3 lane gathers i,f,g via quad-broadcast DPP and updates (c,h) in registers.
__global__ __launch_bounds__(256, 1)
void lstm3_kernel(const float* __restrict__ x, const float* __restrict__ W,
                  const float* __restrict__ U, const float* __restrict__ b,
                  float* __restrict__ out)
{
    const int e    = blockIdx.x;
    const int tid  = threadIdx.x;
    const int wave = tid >> 6, lane = tid & 63;
    const int kq   = lane & 3, jl = lane >> 2;
    const int j    = wave * 16 + jl;
    const bool wr  = (kq == 3);
    const bool u64 = (wave == 1 && lane == 62);

    __shared__ __attribute__((aligned(16))) float vbuf[2][144];
    __shared__ __attribute__((aligned(16))) float ebuf[4];

    // ---- per-thread weights (K-chunk x 4 gates); kk>=32 for kq<3 hits v-pad zeros ----
    float wI[34], wF[34], wG[34], wO[34];
    #pragma unroll
    for (int kk = 0; kk < 34; ++kk) {
        int k = kq * 32 + kk;                 // <= 129 always
        wI[kk] = wrow(W, U, k, j);
        wF[kk] = wrow(W, U, k, 65  + j);
        wG[kk] = wrow(W, U, k, 130 + j);
        wO[kk] = wrow(W, U, k, 195 + j);
    }
    // unit-64 split-K: wave w owns gate-w column (c64), 2 k's per lane + remainder
    const int   c64  = wave * 65 + 64;
    const float xw0  = wrow(W, U, 2 * lane,     c64);
    const float xw1  = wrow(W, U, 2 * lane + 1, c64);
    const float xw2  = (lane < 2) ? wrow(W, U, 128 + lane, c64) : 0.0f;
    const int   posE = inpos(2 * lane);

    const float breg = b[kq * 65 + j];
    const float sk   = (kq == 2) ? 2.0f : 1.0f;   // g-gate: tanh(z) = 2*sigmoid(2z)-1
    const float dk   = 1.0f - sk;

    float b64i = 0, b64f = 0, b64g = 0, b64o = 0;
    if (u64) { b64i = b[64]; b64f = b[129]; b64g = b[194]; b64o = b[259]; }

    float c1 = 0, c2 = 0, c3 = 0, h1 = 0, h2 = 0, h3 = 0;          // unit j (writer lane)
    float ec1 = 0, ec2 = 0, ec3 = 0, eh1 = 0, eh2 = 0, eh3 = 0;    // unit 64 (updater)

    const float* xrow = x   + (size_t)e * SEQ * UNITS;
    float*       orow = out + (size_t)e * SEQ * UNITS;
    const int ipI = inpos(j), ipH = inpos(65 + j);

    // ---- init: zero LDS (pads must be 0), then v = [x0 | 0] ----
    for (int i = tid; i < 2 * 144; i += 256) ((float*)vbuf)[i] = 0.0f;
    if (tid < 4) ebuf[tid] = 0.0f;
    __syncthreads();
    if (wr)  vbuf[0][ipI] = xrow[j];
    if (u64) vbuf[0][72]  = xrow[64];
    __syncthreads();

    // 2-deep x prefetch queues (consume distance ~5 cells >> HBM latency)
    float xq0 = 0, xq1 = 0, ex0 = 0, ex1 = 0;
    if (wr)  { xq0 = xrow[UNITS + j];  xq1 = xrow[2 * UNITS + j]; }
    if (u64) { ex0 = xrow[UNITS + 64]; ex1 = xrow[2 * UNITS + 64]; }

    int cur = 0;
    for (int t = 0; t < SEQ; ++t) {
        #pragma unroll
        for (int cell = 0; cell < 3; ++cell) {
            const float* __restrict__ vc = vbuf[cur];
            float*       __restrict__ vn = vbuf[cur ^ 1];

            // ---------- phase A ----------
            const float* vp = vc + kq * 36;
            float vv[34];
            #pragma unroll
            for (int q8 = 0; q8 < 8; ++q8) {
                float4 f = *(const float4*)(vp + 4 * q8);
                vv[4*q8+0] = f.x; vv[4*q8+1] = f.y; vv[4*q8+2] = f.z; vv[4*q8+3] = f.w;
            }
            { float2 f = *(const float2*)(vp + 32); vv[32] = f.x; vv[33] = f.y; }
            float2 uv  = *(const float2*)(vc + posE);
            float  vex = (lane < 2) ? vc[140 + lane] : 0.0f;

            float aI = 0, aF = 0, aG = 0, aO = 0;
            #pragma unroll
            for (int kk = 0; kk < 34; ++kk) {
                float s = vv[kk];
                aI = fmaf(s, wI[kk], aI);
                aF = fmaf(s, wF[kk], aF);
                aG = fmaf(s, wG[kk], aG);
                aO = fmaf(s, wO[kk], aO);
            }
            float ax = fmaf(uv.x, xw0, fmaf(uv.y, xw1, vex * xw2));
            ax = red64_lane63(ax);
            if (lane == 63) ebuf[wave] = ax;

            aI = red4_all(aI); aF = red4_all(aF); aG = red4_all(aG); aO = red4_all(aO);
            float zsel = ((kq == 0) ? aI : (kq == 1) ? aF : (kq == 2) ? aG : aO) + breg;

            bar_lds();

            // ---------- phase B ----------
            // uniform activation: lane kq holds gate-kq of unit j
            float sg = frcp(1.0f + __expf(-sk * zsel));
            float g  = fmaf(sk, sg, dk);
            float gi = dppmov<0x00>(g);   // quad lane 0 -> all
            float gf = dppmov<0x55>(g);   // quad lane 1 -> all
            float gg = dppmov<0xAA>(g);   // quad lane 2 -> all
            float cprev = (cell == 0) ? c1 : (cell == 1) ? c2 : c3;
            float cnew  = fmaf(gf, cprev, gi * gg);
            float hnew  = g * ftanh(cnew);          // g == o-gate on writer lanes
            if (cell == 0)      { c1 = cnew; h1 = hnew; }
            else if (cell == 1) { c2 = cnew; h2 = hnew; }
            else                { c3 = cnew; h3 = hnew; }

            if (wr) {
                if (cell == 0) {
                    vn[ipI] = h1; vn[ipH] = h2;                 // next v = [h1_new | h2_old]
                    xq1 = (t + 2 < SEQ) ? xrow[(size_t)(t + 2) * UNITS + j] : 0.0f;
                } else if (cell == 1) {
                    vn[ipI] = h2; vn[ipH] = h3;                 // next v = [h2_new | h3_old]
                } else {
                    orow[(size_t)t * UNITS + j] = h3;
                    vn[ipI] = xq0; vn[ipH] = h1;                // next v = [x_{t+1} | h1]
                    xq0 = xq1;
                }
            }
            if (u64) {
                float4 ez = *(const float4*)ebuf;
                float gi4 = fsigmoid(ez.x + b64i);
                float gf4 = fsigmoid(ez.y + b64f);
                float gg4 = ftanh  (ez.z + b64g);
                float go4 = fsigmoid(ez.w + b64o);
                if (cell == 0) {
                    ec1 = fmaf(gf4, ec1, gi4 * gg4); eh1 = go4 * ftanh(ec1);
                    vn[72] = eh1; vn[141] = eh2;
                    ex1 = (t + 2 < SEQ) ? xrow[(size_t)(t + 2) * UNITS + 64] : 0.0f;
                } else if (cell == 1) {
                    ec2 = fmaf(gf4, ec2, gi4 * gg4); eh2 = go4 * ftanh(ec2);
                    vn[72] = eh2; vn[141] = eh3;
                } else {
                    ec3 = fmaf(gf4, ec3, gi4 * gg4); eh3 = go4 * ftanh(ec3);
                    orow[(size_t)t * UNITS + 64] = eh3;
                    vn[72] = ex0; vn[141] = eh1;
                    ex0 = ex1;
                }
            }
            cur ^= 1;
            bar_lds();
        }
    }
}

// Dense head, in place on d_out: out_row = row @ Wd + bd. One thread per row.
__global__ __launch_bounds__(256)
void dense_kernel(float* __restrict__ io,
                  const float* __restrict__ Wd,
                  const float* __restrict__ bd)
{
    __shared__ __attribute__((aligned(16))) float wS[65 * 68];
    __shared__ float bS[65];
    for (int i = threadIdx.x; i < 65 * 65; i += 256) {
        int r = i / 65, c = i - r * 65;
        wS[r * 68 + c] = Wd[i];
    }
    if (threadIdx.x < 65) bS[threadIdx.x] = bd[threadIdx.x];
    __syncthreads();

    const size_t row  = (size_t)blockIdx.x * 256 + threadIdx.x;
    const size_t base = row * 65;

    float r[65];
    #pragma unroll
    for (int k = 0; k < 65; ++k) r[k] = io[base + k];

    for (int ct = 0; ct < 16; ++ct) {
        const int c = ct * 4;
        float a0 = bS[c], a1 = bS[c + 1], a2 = bS[c + 2], a3 = bS[c + 3];
        #pragma unroll
        for (int k = 0; k < 65; ++k) {
            const float4 wv = *reinterpret_cast<const float4*>(&wS[k * 68 + c]);
            a0 += r[k] * wv.x;
            a1 += r[k] * wv.y;
            a2 += r[k] * wv.z;
            a3 += r[k] * wv.w;
        }
        io[base + c]     = a0;
        io[base + c + 1] = a1;
        io[base + c + 2] = a2;
        io[base + c + 3] = a3;
    }
    float a = bS[64];
    #pragma unroll
    for (int k = 0; k < 65; ++k) a += r[k] * wS[k * 68 + 64];
    io[base + 64] = a;
}

extern "C" void kernel_launch(void* const* d_in, const int* in_sizes, int n_in,
                              void* d_out, int out_size, void* d_ws, size_t ws_size,
                              hipStream_t stream)
{
    const float* x  = (const float*)d_in[0];
    const float* W  = (const float*)d_in[1];
    const float* U  = (const float*)d_in[2];
    const float* b  = (const float*)d_in[3];
    const float* Wd = (const float*)d_in[4];
    const float* bd = (const float*)d_in[5];
    float* out = (float*)d_out;

    hipLaunchKernelGGL(lstm3_kernel, dim3(BATCH), dim3(256), 0, stream, x, W, U, b, out);
    hipLaunchKernelGGL(dense_kernel, dim3(1600), dim3(256), 0, stream, out, Wd, bd);
}